// Round 7
// baseline (97.109 us; speedup 1.0000x reference)
//
#include <hip/hip_runtime.h>

#define KIN 1024

__device__ __forceinline__ float4 f4add(float4 a, float4 b) {
    return make_float4(a.x + b.x, a.y + b.y, a.z + b.z, a.w + b.w);
}

// constant-address-space pointer -> uniform loads become s_load (scalar pipe)
typedef const __attribute__((address_space(4))) float cfloat;
__device__ __forceinline__ cfloat* as_const(const float* p) {
    return (cfloat*)(unsigned long long)(uintptr_t)p;
}

// ---------------------------------------------------------------------------
// K0: blocks [0,16): repack W (64d x 256k) -> Wq[kq][d] float4.
//     blocks [16,272): pe partial sums, task=(c,pr): stage 16 rows of residue
//     pr in LDS (pad 8 -> conflict-free), emit pe_cs[c][pr][256] and
//     pe_rs[c][row][16] for the 16 rows.
// ---------------------------------------------------------------------------
__global__ __launch_bounds__(256, 6) void k0_prep(
    const float* __restrict__ Wv, const float* __restrict__ Wh,
    const float* __restrict__ pe,
    float4* __restrict__ Wqv, float4* __restrict__ Wqh,
    float* __restrict__ pe_cs, float* __restrict__ pe_rs)
{
    const int blk = blockIdx.x, t = threadIdx.x;
    if (blk < 16) {
        int idx = blk * 256 + t;
        int kq = idx >> 6, d = idx & 63;
        Wqv[idx] = *(const float4*)(Wv + d * 256 + 4 * kq);
        Wqh[idx] = *(const float4*)(Wh + d * 256 + 4 * kq);
        return;
    }

    __shared__ float srow[16][264];
    __shared__ float cpart[4][256];

    const int task = blk - 16;                 // 0..255
    const int c = task >> 4, pr = task & 15;
    const float* ib = pe + (size_t)c * 65536;
    const int w = t >> 6, l = t & 63;

    float4 cacc = make_float4(0.f, 0.f, 0.f, 0.f);
    #pragma unroll
    for (int j = 0; j < 4; ++j) {
        const int lr = 4 * w + j;
        float4 v = *(const float4*)(ib + (size_t)(pr + 16 * lr) * 256 + 4 * l);
        cacc = f4add(cacc, v);
        *(float4*)&srow[lr][4 * l] = v;
    }
    *(float4*)&cpart[w][4 * l] = cacc;
    __syncthreads();

    {   // rowsum: thread (lr, pc)
        const int lr = t >> 4, pc = t & 15;
        float s = 0.f;
        #pragma unroll
        for (int i = 0; i < 16; ++i) s += srow[lr][pc + 16 * i];
        const int grow = pr + 16 * lr;
        pe_rs[((size_t)c * 256 + grow) * 16 + pc] = s;
    }
    {   // colsum: thread = col
        float s = cpart[0][t] + cpart[1][t] + cpart[2][t] + cpart[3][t];
        pe_cs[((size_t)c * 16 + pr) * 256 + t] = s;
    }
}

// ---------------------------------------------------------------------------
// K1: block = (bc, pr), 4096 blocks. Stage the 16 rows of residue pr in LDS
// once; colsum from register partials (cross-wave via cpart), rowsum from
// strided LDS reads (no shuffles). pe partials folded at store -> cs_buf /
// rs_buf hold FINAL sums.
// ---------------------------------------------------------------------------
__global__ __launch_bounds__(256, 6) void k1_reduce(
    const float* __restrict__ x,
    const float* __restrict__ pe_cs, const float* __restrict__ pe_rs,
    float* __restrict__ cs_buf, float* __restrict__ rs_buf)
{
    __shared__ float srow[16][264];
    __shared__ float cpart[4][256];

    const int blk = blockIdx.x;                 // 0..4095
    const int img = blk >> 4, pr = blk & 15, c = img & 15;
    const float* ib = x + (size_t)img * 65536;
    const int t = threadIdx.x, w = t >> 6, l = t & 63;

    float4 cacc = make_float4(0.f, 0.f, 0.f, 0.f);
    #pragma unroll
    for (int j = 0; j < 4; ++j) {
        const int lr = 4 * w + j;
        float4 v = *(const float4*)(ib + (size_t)(pr + 16 * lr) * 256 + 4 * l);
        cacc = f4add(cacc, v);
        *(float4*)&srow[lr][4 * l] = v;
    }
    *(float4*)&cpart[w][4 * l] = cacc;
    __syncthreads();

    {   // rowsum + pe fold
        const int lr = t >> 4, pc = t & 15;
        float s = 0.f;
        #pragma unroll
        for (int i = 0; i < 16; ++i) s += srow[lr][pc + 16 * i];
        const int grow = pr + 16 * lr;
        rs_buf[(size_t)img * 4096 + grow * 16 + pc] =
            s + pe_rs[((size_t)c * 256 + grow) * 16 + pc];
    }
    {   // colsum + pe fold
        float s = cpart[0][t] + cpart[1][t] + cpart[2][t] + cpart[3][t];
        cs_buf[(size_t)img * 4096 + pr * 256 + t] =
            s + pe_cs[((size_t)c * 16 + pr) * 256 + t];
    }
}

// ---------------------------------------------------------------------------
// K1c: block = (bc, mat), 512 blocks. lane = d; wave w owns segs 4w..4w+3.
// W fragments: coalesced VMEM from Wq. cs/rs operands are wave-uniform ->
// loaded through constant address space (s_load, scalar pipe). Zero LDS.
//   V: o = pr*256 + seg*16 + pc     H: o = seg*256 + pr*16 + pc
// ---------------------------------------------------------------------------
__global__ __launch_bounds__(256) void k1c(
    const float* __restrict__ cs_buf, const float* __restrict__ rs_buf,
    const float4* __restrict__ Wqv, const float4* __restrict__ Wqh,
    const float* __restrict__ bv, const float* __restrict__ bh,
    float* __restrict__ vcomp, float* __restrict__ hcomp)
{
    const int blk = blockIdx.x;
    const int bc = blk >> 1, mat = blk & 1;
    const int t = threadIdx.x, w = t >> 6, l = t & 63;

    cfloat* S = as_const((mat ? rs_buf : cs_buf) + (size_t)bc * 4096);
    const float4* Wq = mat ? Wqh : Wqv;
    const int sp = mat ? 16 : 256;     // stride of pr
    const int ss = mat ? 256 : 16;     // stride of seg
    const int s0 = 4 * w;

    float acc[4] = {0.f, 0.f, 0.f, 0.f};
    #pragma unroll 4
    for (int kq = 0; kq < 64; ++kq) {
        float4 wq = Wq[kq * 64 + l];
        const int pr = kq >> 2, pc4 = (kq & 3) * 4;
        const int base = pr * sp + pc4;
        #pragma unroll
        for (int si = 0; si < 4; ++si) {
            const int o = base + (s0 + si) * ss;
            acc[si] += wq.x * S[o] + wq.y * S[o + 1]
                     + wq.z * S[o + 2] + wq.w * S[o + 3];
        }
    }

    const float b16 = 16.f * (mat ? bh[l] : bv[l]);
    float* dst = (mat ? hcomp : vcomp) + (size_t)bc * KIN;
    #pragma unroll
    for (int si = 0; si < 4; ++si)
        dst[(s0 + si) * 64 + l] = acc[si] + b16;
}

// ---------------------------------------------------------------------------
// K2: P[ks][bc][r][n] = sum_{k in ks-chunk} A[bc][k] * B[r][n][k]
// Tile 64bc x 64n x 3r, micro 4x3x4. grid (4 n-tiles, 4 bc-tiles * KS, 2).
// ---------------------------------------------------------------------------
__global__ __launch_bounds__(256) void k2_proj(
    const float* __restrict__ vcomp, const float* __restrict__ hcomp,
    const float* __restrict__ Vw, const float* __restrict__ Hw,
    float* __restrict__ Vp, float* __restrict__ Hp, int KSplit, int KC)
{
    __shared__ float sA[32][68];
    __shared__ float sB[32][196];

    const int mat = blockIdx.z;
    const float* A = mat ? hcomp : vcomp;
    const float* B = mat ? Hw : Vw;
    float*       P = mat ? Hp : Vp;

    const int n0  = blockIdx.x * 64;
    const int bct = blockIdx.y / KSplit, ks = blockIdx.y % KSplit;
    const int bc0 = bct * 64;
    const int t   = threadIdx.x, tb = t >> 4, tn = t & 15;

    float acc[4][3][4];
    #pragma unroll
    for (int i = 0; i < 4; ++i)
        #pragma unroll
        for (int r = 0; r < 3; ++r)
            #pragma unroll
            for (int j = 0; j < 4; ++j) acc[i][r][j] = 0.f;

    const int nch = KC >> 5;
    for (int ch = 0; ch < nch; ++ch) {
        const int k0 = ks * KC + ch * 32;
        #pragma unroll
        for (int s = 0; s < 2; ++s) {               // A: 64x32
            int q = t + s * 256;
            int bcl = q >> 3, kq = q & 7;
            float4 v = *(const float4*)(A + (size_t)(bc0 + bcl) * KIN + k0 + 4 * kq);
            sA[4*kq+0][bcl] = v.x; sA[4*kq+1][bcl] = v.y;
            sA[4*kq+2][bcl] = v.z; sA[4*kq+3][bcl] = v.w;
        }
        #pragma unroll
        for (int s = 0; s < 6; ++s) {               // B: 192x32
            int q = t + s * 256;
            int rr = q >> 3, kq = q & 7;
            int r = rr >> 6, nn = rr & 63;
            float4 v = *(const float4*)(B + ((size_t)(r * 256 + n0 + nn)) * KIN + k0 + 4 * kq);
            sB[4*kq+0][rr] = v.x; sB[4*kq+1][rr] = v.y;
            sB[4*kq+2][rr] = v.z; sB[4*kq+3][rr] = v.w;
        }
        __syncthreads();

        #pragma unroll 8
        for (int kk = 0; kk < 32; ++kk) {
            float4 av = *(const float4*)&sA[kk][4 * tb];
            float4 b0 = *(const float4*)&sB[kk][0 * 64 + 4 * tn];
            float4 b1 = *(const float4*)&sB[kk][1 * 64 + 4 * tn];
            float4 b2 = *(const float4*)&sB[kk][2 * 64 + 4 * tn];
            float a_[4] = {av.x, av.y, av.z, av.w};
            float b_[3][4] = {{b0.x,b0.y,b0.z,b0.w},{b1.x,b1.y,b1.z,b1.w},{b2.x,b2.y,b2.z,b2.w}};
            #pragma unroll
            for (int i = 0; i < 4; ++i)
                #pragma unroll
                for (int r = 0; r < 3; ++r)
                    #pragma unroll
                    for (int j = 0; j < 4; ++j)
                        acc[i][r][j] += a_[i] * b_[r][j];
        }
        __syncthreads();
    }

    #pragma unroll
    for (int i = 0; i < 4; ++i)
        #pragma unroll
        for (int r = 0; r < 3; ++r) {
            float4 o = make_float4(acc[i][r][0], acc[i][r][1], acc[i][r][2], acc[i][r][3]);
            *(float4*)(P + (((size_t)ks * 256 + bc0 + 4 * tb + i) * 3 + r) * 256 + n0 + 4 * tn) = o;
        }
}

// ---------------------------------------------------------------------------
// K3: reduce split-K partials (+bias); out = V H^T (rank 3), float4 stores.
// grid (4 x 256): 64-row tiles, wave = one output row per iteration.
// ---------------------------------------------------------------------------
__global__ __launch_bounds__(256) void k3_outer(
    const float* __restrict__ Vp, const float* __restrict__ Hp,
    const float* __restrict__ Vb, const float* __restrict__ Hb,
    float* __restrict__ out, int KSplit)
{
    __shared__ float sh[3][256];
    __shared__ float sv[3][64];

    const int bc = blockIdx.y, nt = blockIdx.x, t = threadIdx.x;

    #pragma unroll
    for (int r = 0; r < 3; ++r) {
        float a = Hb[r * 256 + t];
        for (int ks = 0; ks < KSplit; ++ks)
            a += Hp[(((size_t)ks * 256 + bc) * 3 + r) * 256 + t];
        sh[r][t] = a;
    }
    if (t < 192) {
        int r = t >> 6, nn = t & 63;
        float a = Vb[r * 256 + nt * 64 + nn];
        for (int ks = 0; ks < KSplit; ++ks)
            a += Vp[(((size_t)ks * 256 + bc) * 3 + r) * 256 + nt * 64 + nn];
        sv[r][nn] = a;
    }
    __syncthreads();

    const int mq = t & 63, rg = t >> 6;
    float4 h0 = *(const float4*)&sh[0][4 * mq];
    float4 h1 = *(const float4*)&sh[1][4 * mq];
    float4 h2 = *(const float4*)&sh[2][4 * mq];
    float* ob = out + ((size_t)bc * 256 + nt * 64) * 256;
    #pragma unroll 4
    for (int j = 0; j < 16; ++j) {
        const int nn = 4 * j + rg;
        const float v0 = sv[0][nn], v1 = sv[1][nn], v2 = sv[2][nn];
        float4 o;
        o.x = v0 * h0.x + v1 * h1.x + v2 * h2.x;
        o.y = v0 * h0.y + v1 * h1.y + v2 * h2.y;
        o.z = v0 * h0.z + v1 * h1.z + v2 * h2.z;
        o.w = v0 * h0.w + v1 * h1.w + v2 * h2.w;
        *(float4*)(ob + nn * 256 + 4 * mq) = o;
    }
}

extern "C" void kernel_launch(void* const* d_in, const int* in_sizes, int n_in,
                              void* d_out, int out_size, void* d_ws, size_t ws_size,
                              hipStream_t stream)
{
    const float* x  = (const float*)d_in[0];
    const float* pe = (const float*)d_in[1];
    const float* Wv = (const float*)d_in[2];
    const float* bv = (const float*)d_in[3];
    const float* Wh = (const float*)d_in[4];
    const float* bh = (const float*)d_in[5];
    const float* Vw = (const float*)d_in[6];
    const float* Vb = (const float*)d_in[7];
    const float* Hw = (const float*)d_in[8];
    const float* Hb = (const float*)d_in[9];
    float* out = (float*)d_out;

    // ws layout (floats)
    float* ws     = (float*)d_ws;
    float* vcomp  = ws;                  // 262144
    float* hcomp  = ws + 262144;         // 262144
    float* wqv    = ws + 524288;         // 16384
    float* wqh    = ws + 540672;         // 16384
    float* pe_cs  = ws + 557056;         // 65536
    float* pe_rs  = ws + 622592;         // 65536
    float* cs_buf = ws + 688128;         // 256*4096 = 1048576
    float* rs_buf = ws + 1736704;        // 1048576
    float* rest   = ws + 2785280;        // split-K partials

    int KS = 1;
    if      (ws_size >= (2785280ull + 8 * 393216ull) * 4) KS = 8;
    else if (ws_size >= (2785280ull + 4 * 393216ull) * 4) KS = 4;
    else if (ws_size >= (2785280ull + 2 * 393216ull) * 4) KS = 2;
    const int KC = KIN / KS;

    float* Vp = rest;
    float* Hp = rest + (size_t)KS * 196608;

    k0_prep<<<272, 256, 0, stream>>>(Wv, Wh, pe, (float4*)wqv, (float4*)wqh,
                                     pe_cs, pe_rs);
    k1_reduce<<<4096, 256, 0, stream>>>(x, pe_cs, pe_rs, cs_buf, rs_buf);
    k1c<<<512, 256, 0, stream>>>(cs_buf, rs_buf,
                                 (const float4*)wqv, (const float4*)wqh,
                                 bv, bh, vcomp, hcomp);
    k2_proj<<<dim3(4, 4 * KS, 2), 256, 0, stream>>>(vcomp, hcomp, Vw, Hw,
                                                    Vp, Hp, KS, KC);
    k3_outer<<<dim3(4, 256), 256, 0, stream>>>(Vp, Hp, Vb, Hb, out, KS);
}

// Round 8
// 82.257 us; speedup vs baseline: 1.1806x; 1.1806x over previous
//
#include <hip/hip_runtime.h>

#define KIN 1024

__device__ __forceinline__ float4 f4add(float4 a, float4 b) {
    return make_float4(a.x + b.x, a.y + b.y, a.z + b.z, a.w + b.w);
}
__device__ __forceinline__ float f4dot(float4 a, float4 b) {
    return a.x * b.x + a.y * b.y + a.z * b.z + a.w * b.w;
}

// ---------------------------------------------------------------------------
// K1: single-pass reduction. Block = (img, pr) over 272 images (0..255 =
// x[bc], 256..271 = pe[c]) x 16 residues. The 16 rows of residue pr ARE the
// colsum[pr] reduction set, and each row is loaded whole so its rowsum comes
// from a 4-level shfl_xor butterfly in the same pass. x/pe read ONCE (~70MB).
// Blocks [0,16) repack W -> Wq[kq][d] float4 for K1c's coalesced reads.
// ---------------------------------------------------------------------------
__global__ __launch_bounds__(256) void k1_fused(
    const float* __restrict__ x, const float* __restrict__ pe,
    const float* __restrict__ Wv, const float* __restrict__ Wh,
    float4* __restrict__ Wqv, float4* __restrict__ Wqh,
    float* __restrict__ colsum_buf, float* __restrict__ rowsum_buf)
{
    const int blk = blockIdx.x, t = threadIdx.x;

    if (blk < 16) {                                  // --- W repack ---
        int idx = blk * 256 + t;                     // 0..4095
        int kq = idx >> 6, d = idx & 63;
        Wqv[idx] = *(const float4*)(Wv + d * 256 + 4 * kq);
        Wqh[idx] = *(const float4*)(Wh + d * 256 + 4 * kq);
        return;
    }

    __shared__ float cpart[4][256];

    const int b2 = blk - 16;                         // 0..4351
    const int img = b2 >> 4, pr = b2 & 15;
    const float* ib = (img < 256) ? (x + (size_t)img * 65536)
                                  : (pe + (size_t)(img - 256) * 65536);
    const int w = t >> 6, l = t & 63;

    // wave w handles rows pr + 64w + 16j (j=0..3); lane l holds cols 4l..4l+3
    float4 v[4];
    const float* base = ib + (size_t)(pr + 64 * w) * 256 + 4 * l;
    #pragma unroll
    for (int j = 0; j < 4; ++j)
        v[j] = *(const float4*)(base + j * 4096);

    // colsum partial (register) -> LDS for cross-wave combine
    *(float4*)&cpart[w][4 * l] = f4add(f4add(v[0], v[1]), f4add(v[2], v[3]));

    // rowsum: butterfly over masks 4..32 leaves lane c (=l&3) holding
    // float4 = rowsum[row][4c..4c+3]; lanes 0..3 store 64B contiguous.
    #pragma unroll
    for (int j = 0; j < 4; ++j) {
        float4 s = v[j];
        #pragma unroll
        for (int m = 4; m <= 32; m <<= 1) {
            s.x += __shfl_xor(s.x, m);
            s.y += __shfl_xor(s.y, m);
            s.z += __shfl_xor(s.z, m);
            s.w += __shfl_xor(s.w, m);
        }
        if (l < 4) {
            const int row = pr + 64 * w + 16 * j;
            *(float4*)(rowsum_buf + (size_t)img * 4096 + row * 16 + 4 * l) = s;
        }
    }
    __syncthreads();

    colsum_buf[(size_t)img * 4096 + pr * 256 + t] =
        cpart[0][t] + cpart[1][t] + cpart[2][t] + cpart[3][t];
}

// ---------------------------------------------------------------------------
// K1c: per bc, project (colsum+pe_colsum) with Wqv and (rowsum+pe_rowsum)
// with Wqh -> vcomp/hcomp (pe + 16x bias folded). 16 waves: V waves 0..7
// own kq-eighths (all 16 segs), H waves 8..15 likewise. LDS broadcast reads.
// ---------------------------------------------------------------------------
__global__ __launch_bounds__(1024) void k1c(
    const float* __restrict__ colsum_buf, const float* __restrict__ rowsum_buf,
    const float4* __restrict__ Wqv, const float4* __restrict__ Wqh,
    const float* __restrict__ bv, const float* __restrict__ bh,
    float* __restrict__ vcomp, float* __restrict__ hcomp)
{
    __shared__ float cs[16][256];
    __shared__ float rs[256][16];
    __shared__ float vp[8][1024];
    __shared__ float hp[8][1024];

    const int bc = blockIdx.x, c = bc & 15, t = threadIdx.x;

    {
        float4 a = ((const float4*)(colsum_buf + (size_t)bc * 4096))[t];
        float4 p = ((const float4*)(colsum_buf + (size_t)(256 + c) * 4096))[t];
        ((float4*)cs)[t] = f4add(a, p);
        float4 b = ((const float4*)(rowsum_buf + (size_t)bc * 4096))[t];
        float4 q = ((const float4*)(rowsum_buf + (size_t)(256 + c) * 4096))[t];
        ((float4*)rs)[t] = f4add(b, q);
    }
    __syncthreads();

    const int w = t >> 6, l = t & 63;
    if (w < 8) {
        const int kq0 = w * 8;
        float acc[16];
        #pragma unroll
        for (int s = 0; s < 16; ++s) acc[s] = 0.f;
        #pragma unroll 2
        for (int kq = kq0; kq < kq0 + 8; ++kq) {
            float4 wq = Wqv[kq * 64 + l];
            const int pr = kq >> 2, pc4 = (kq & 3) * 4;
            #pragma unroll
            for (int s = 0; s < 16; ++s)
                acc[s] += f4dot(wq, *(const float4*)&cs[pr][s * 16 + pc4]);
        }
        #pragma unroll
        for (int s = 0; s < 16; ++s) vp[w][s * 64 + l] = acc[s];
    } else {
        const int kq0 = (w - 8) * 8;
        float acc[16];
        #pragma unroll
        for (int s = 0; s < 16; ++s) acc[s] = 0.f;
        #pragma unroll 2
        for (int kq = kq0; kq < kq0 + 8; ++kq) {
            float4 wq = Wqh[kq * 64 + l];
            const int pr = kq >> 2, pc4 = (kq & 3) * 4;
            #pragma unroll
            for (int s = 0; s < 16; ++s)
                acc[s] += f4dot(wq, *(const float4*)&rs[s * 16 + pr][pc4]);
        }
        #pragma unroll
        for (int s = 0; s < 16; ++s) hp[w - 8][s * 64 + l] = acc[s];
    }
    __syncthreads();

    {
        float v = 0.f, hsum = 0.f;
        #pragma unroll
        for (int k = 0; k < 8; ++k) { v += vp[k][t]; hsum += hp[k][t]; }
        vcomp[(size_t)bc * KIN + t] = v + 16.f * bv[t & 63];
        hcomp[(size_t)bc * KIN + t] = hsum + 16.f * bh[t & 63];
    }
}

// ---------------------------------------------------------------------------
// K2: P[ks][bc][r][n] = sum_{k in ks-chunk} A[bc][k] * B[r][n][k]
// Tile 64bc x 64n x 3r, micro 4x3x4. grid (4 n-tiles, 4 bc-tiles * KS, 2).
// ---------------------------------------------------------------------------
__global__ __launch_bounds__(256) void k2_proj(
    const float* __restrict__ vcomp, const float* __restrict__ hcomp,
    const float* __restrict__ Vw, const float* __restrict__ Hw,
    float* __restrict__ Vp, float* __restrict__ Hp, int KSplit, int KC)
{
    __shared__ float sA[32][68];
    __shared__ float sB[32][196];

    const int mat = blockIdx.z;
    const float* A = mat ? hcomp : vcomp;
    const float* B = mat ? Hw : Vw;
    float*       P = mat ? Hp : Vp;

    const int n0  = blockIdx.x * 64;
    const int bct = blockIdx.y / KSplit, ks = blockIdx.y % KSplit;
    const int bc0 = bct * 64;
    const int t   = threadIdx.x, tb = t >> 4, tn = t & 15;

    float acc[4][3][4];
    #pragma unroll
    for (int i = 0; i < 4; ++i)
        #pragma unroll
        for (int r = 0; r < 3; ++r)
            #pragma unroll
            for (int j = 0; j < 4; ++j) acc[i][r][j] = 0.f;

    const int nch = KC >> 5;
    for (int ch = 0; ch < nch; ++ch) {
        const int k0 = ks * KC + ch * 32;
        #pragma unroll
        for (int s = 0; s < 2; ++s) {               // A: 64x32
            int q = t + s * 256;
            int bcl = q >> 3, kq = q & 7;
            float4 v = *(const float4*)(A + (size_t)(bc0 + bcl) * KIN + k0 + 4 * kq);
            sA[4*kq+0][bcl] = v.x; sA[4*kq+1][bcl] = v.y;
            sA[4*kq+2][bcl] = v.z; sA[4*kq+3][bcl] = v.w;
        }
        #pragma unroll
        for (int s = 0; s < 6; ++s) {               // B: 192x32
            int q = t + s * 256;
            int rr = q >> 3, kq = q & 7;
            int r = rr >> 6, nn = rr & 63;
            float4 v = *(const float4*)(B + ((size_t)(r * 256 + n0 + nn)) * KIN + k0 + 4 * kq);
            sB[4*kq+0][rr] = v.x; sB[4*kq+1][rr] = v.y;
            sB[4*kq+2][rr] = v.z; sB[4*kq+3][rr] = v.w;
        }
        __syncthreads();

        #pragma unroll 8
        for (int kk = 0; kk < 32; ++kk) {
            float4 av = *(const float4*)&sA[kk][4 * tb];
            float4 b0 = *(const float4*)&sB[kk][0 * 64 + 4 * tn];
            float4 b1 = *(const float4*)&sB[kk][1 * 64 + 4 * tn];
            float4 b2 = *(const float4*)&sB[kk][2 * 64 + 4 * tn];
            float a_[4] = {av.x, av.y, av.z, av.w};
            float b_[3][4] = {{b0.x,b0.y,b0.z,b0.w},{b1.x,b1.y,b1.z,b1.w},{b2.x,b2.y,b2.z,b2.w}};
            #pragma unroll
            for (int i = 0; i < 4; ++i)
                #pragma unroll
                for (int r = 0; r < 3; ++r)
                    #pragma unroll
                    for (int j = 0; j < 4; ++j)
                        acc[i][r][j] += a_[i] * b_[r][j];
        }
        __syncthreads();
    }

    #pragma unroll
    for (int i = 0; i < 4; ++i)
        #pragma unroll
        for (int r = 0; r < 3; ++r) {
            float4 o = make_float4(acc[i][r][0], acc[i][r][1], acc[i][r][2], acc[i][r][3]);
            *(float4*)(P + (((size_t)ks * 256 + bc0 + 4 * tb + i) * 3 + r) * 256 + n0 + 4 * tn) = o;
        }
}

// ---------------------------------------------------------------------------
// K3: reduce split-K partials (+bias); out = V H^T (rank 3), float4 stores.
// grid (4 x 256): 64-row tiles; 8x fewer store instrs than b32 version.
// ---------------------------------------------------------------------------
__global__ __launch_bounds__(256) void k3_outer(
    const float* __restrict__ Vp, const float* __restrict__ Hp,
    const float* __restrict__ Vb, const float* __restrict__ Hb,
    float* __restrict__ out, int KSplit)
{
    __shared__ float sh[3][256];
    __shared__ float sv[3][64];

    const int bc = blockIdx.y, nt = blockIdx.x, t = threadIdx.x;

    #pragma unroll
    for (int r = 0; r < 3; ++r) {
        float a = Hb[r * 256 + t];
        for (int ks = 0; ks < KSplit; ++ks)
            a += Hp[(((size_t)ks * 256 + bc) * 3 + r) * 256 + t];
        sh[r][t] = a;
    }
    if (t < 192) {
        int r = t >> 6, nn = t & 63;
        float a = Vb[r * 256 + nt * 64 + nn];
        for (int ks = 0; ks < KSplit; ++ks)
            a += Vp[(((size_t)ks * 256 + bc) * 3 + r) * 256 + nt * 64 + nn];
        sv[r][nn] = a;
    }
    __syncthreads();

    const int mq = t & 63, rg = t >> 6;
    float4 h0 = *(const float4*)&sh[0][4 * mq];
    float4 h1 = *(const float4*)&sh[1][4 * mq];
    float4 h2 = *(const float4*)&sh[2][4 * mq];
    float* ob = out + ((size_t)bc * 256 + nt * 64) * 256;
    #pragma unroll 4
    for (int j = 0; j < 16; ++j) {
        const int nn = 4 * j + rg;
        const float v0 = sv[0][nn], v1 = sv[1][nn], v2 = sv[2][nn];
        float4 o;
        o.x = v0 * h0.x + v1 * h1.x + v2 * h2.x;
        o.y = v0 * h0.y + v1 * h1.y + v2 * h2.y;
        o.z = v0 * h0.z + v1 * h1.z + v2 * h2.z;
        o.w = v0 * h0.w + v1 * h1.w + v2 * h2.w;
        *(float4*)(ob + nn * 256 + 4 * mq) = o;
    }
}

extern "C" void kernel_launch(void* const* d_in, const int* in_sizes, int n_in,
                              void* d_out, int out_size, void* d_ws, size_t ws_size,
                              hipStream_t stream)
{
    const float* x  = (const float*)d_in[0];
    const float* pe = (const float*)d_in[1];
    const float* Wv = (const float*)d_in[2];
    const float* bv = (const float*)d_in[3];
    const float* Wh = (const float*)d_in[4];
    const float* bh = (const float*)d_in[5];
    const float* Vw = (const float*)d_in[6];
    const float* Vb = (const float*)d_in[7];
    const float* Hw = (const float*)d_in[8];
    const float* Hb = (const float*)d_in[9];
    float* out = (float*)d_out;

    // ws layout (floats)
    float* ws         = (float*)d_ws;
    float* vcomp      = ws;                    // 262144
    float* hcomp      = ws + 262144;           // 262144
    float* wqv        = ws + 524288;           // 16384
    float* wqh        = ws + 540672;           // 16384
    float* colsum_buf = ws + 557056;           // 272*4096 = 1114112
    float* rowsum_buf = ws + 1671168;          // 1114112
    float* rest       = ws + 2785280;          // split-K partials

    int KS = 1;
    if      (ws_size >= (2785280ull + 8 * 393216ull) * 4) KS = 8;
    else if (ws_size >= (2785280ull + 4 * 393216ull) * 4) KS = 4;
    else if (ws_size >= (2785280ull + 2 * 393216ull) * 4) KS = 2;
    const int KC = KIN / KS;

    float* Vp = rest;
    float* Hp = rest + (size_t)KS * 196608;

    k1_fused<<<16 + 4352, 256, 0, stream>>>(x, pe, Wv, Wh,
                                            (float4*)wqv, (float4*)wqh,
                                            colsum_buf, rowsum_buf);
    k1c<<<256, 1024, 0, stream>>>(colsum_buf, rowsum_buf,
                                  (const float4*)wqv, (const float4*)wqh,
                                  bv, bh, vcomp, hcomp);
    k2_proj<<<dim3(4, 4 * KS, 2), 256, 0, stream>>>(vcomp, hcomp, Vw, Hw,
                                                    Vp, Hp, KS, KC);
    k3_outer<<<dim3(4, 256), 256, 0, stream>>>(Vp, Hp, Vb, Hb, out, KS);
}

// Round 9
// 67.563 us; speedup vs baseline: 1.4373x; 1.2175x over previous
//
#include <hip/hip_runtime.h>

#define KIN 1024

__device__ __forceinline__ float4 f4add(float4 a, float4 b) {
    return make_float4(a.x + b.x, a.y + b.y, a.z + b.z, a.w + b.w);
}
__device__ __forceinline__ float f4dot(float4 a, float4 b) {
    return a.x * b.x + a.y * b.y + a.z * b.z + a.w * b.w;
}

// ---------------------------------------------------------------------------
// K1: single-pass reduction. Block = (img, pr) over 272 images (0..255 =
// x[bc], 256..271 = pe[c]) x 16 residues. The 16 rows of residue pr ARE the
// colsum[pr] reduction set; rowsum via LDS transpose (4 b128 writes + 16 b32
// strided reads per thread, <=2-way banks) instead of shfl butterfly.
// Blocks [0,16) repack W -> Wq[kq][d] float4 for K1c's coalesced reads.
// ---------------------------------------------------------------------------
__global__ __launch_bounds__(256) void k1_fused(
    const float* __restrict__ x, const float* __restrict__ pe,
    const float* __restrict__ Wv, const float* __restrict__ Wh,
    float4* __restrict__ Wqv, float4* __restrict__ Wqh,
    float* __restrict__ colsum_buf, float* __restrict__ rowsum_buf)
{
    const int blk = blockIdx.x, t = threadIdx.x;

    if (blk < 16) {                                  // --- W repack ---
        int idx = blk * 256 + t;                     // 0..4095
        int kq = idx >> 6, d = idx & 63;
        Wqv[idx] = *(const float4*)(Wv + d * 256 + 4 * kq);
        Wqh[idx] = *(const float4*)(Wh + d * 256 + 4 * kq);
        return;
    }

    __shared__ float srow[16][264];   // 16 rows x 256 cols (+8 pad)
    __shared__ float cpart[4][256];

    const int b2 = blk - 16;                         // 0..4351
    const int img = b2 >> 4, pr = b2 & 15;
    const float* ib = (img < 256) ? (x + (size_t)img * 65536)
                                  : (pe + (size_t)(img - 256) * 65536);
    const int w = t >> 6, l = t & 63;

    // wave w owns local rows 4w..4w+3 = global rows pr + 16*(4w+j)
    float4 v[4];
    const float* base = ib + (size_t)(pr + 64 * w) * 256 + 4 * l;
    #pragma unroll
    for (int j = 0; j < 4; ++j)
        v[j] = *(const float4*)(base + j * 4096);

    // colsum partial (register) -> LDS for cross-wave combine
    *(float4*)&cpart[w][4 * l] = f4add(f4add(v[0], v[1]), f4add(v[2], v[3]));

    // stage rows for the transpose-read rowsum
    #pragma unroll
    for (int j = 0; j < 4; ++j)
        *(float4*)&srow[4 * w + j][4 * l] = v[j];
    __syncthreads();

    {   // rowsum: thread (lr, pc) sums 16 strided elements of one row
        const int lr = t >> 4, pc = t & 15;
        float s = 0.f;
        #pragma unroll
        for (int i = 0; i < 16; ++i) s += srow[lr][pc + 16 * i];
        const int grow = pr + 16 * lr;
        rowsum_buf[(size_t)img * 4096 + grow * 16 + pc] = s;
    }
    {   // colsum combine
        colsum_buf[(size_t)img * 4096 + pr * 256 + t] =
            cpart[0][t] + cpart[1][t] + cpart[2][t] + cpart[3][t];
    }
}

// ---------------------------------------------------------------------------
// K1c: per bc, project (colsum+pe_colsum) with Wqv and (rowsum+pe_rowsum)
// with Wqh -> vcomp/hcomp (pe + 16x bias folded). 16 waves: V waves 0..7
// own kq-eighths (all 16 segs), H waves 8..15 likewise. LDS broadcast reads.
// ---------------------------------------------------------------------------
__global__ __launch_bounds__(1024) void k1c(
    const float* __restrict__ colsum_buf, const float* __restrict__ rowsum_buf,
    const float4* __restrict__ Wqv, const float4* __restrict__ Wqh,
    const float* __restrict__ bv, const float* __restrict__ bh,
    float* __restrict__ vcomp, float* __restrict__ hcomp)
{
    __shared__ float cs[16][256];
    __shared__ float rs[256][16];
    __shared__ float vp[8][1024];
    __shared__ float hp[8][1024];

    const int bc = blockIdx.x, c = bc & 15, t = threadIdx.x;

    {
        float4 a = ((const float4*)(colsum_buf + (size_t)bc * 4096))[t];
        float4 p = ((const float4*)(colsum_buf + (size_t)(256 + c) * 4096))[t];
        ((float4*)cs)[t] = f4add(a, p);
        float4 b = ((const float4*)(rowsum_buf + (size_t)bc * 4096))[t];
        float4 q = ((const float4*)(rowsum_buf + (size_t)(256 + c) * 4096))[t];
        ((float4*)rs)[t] = f4add(b, q);
    }
    __syncthreads();

    const int w = t >> 6, l = t & 63;
    if (w < 8) {
        const int kq0 = w * 8;
        float acc[16];
        #pragma unroll
        for (int s = 0; s < 16; ++s) acc[s] = 0.f;
        #pragma unroll 2
        for (int kq = kq0; kq < kq0 + 8; ++kq) {
            float4 wq = Wqv[kq * 64 + l];
            const int pr = kq >> 2, pc4 = (kq & 3) * 4;
            #pragma unroll
            for (int s = 0; s < 16; ++s)
                acc[s] += f4dot(wq, *(const float4*)&cs[pr][s * 16 + pc4]);
        }
        #pragma unroll
        for (int s = 0; s < 16; ++s) vp[w][s * 64 + l] = acc[s];
    } else {
        const int kq0 = (w - 8) * 8;
        float acc[16];
        #pragma unroll
        for (int s = 0; s < 16; ++s) acc[s] = 0.f;
        #pragma unroll 2
        for (int kq = kq0; kq < kq0 + 8; ++kq) {
            float4 wq = Wqh[kq * 64 + l];
            const int pr = kq >> 2, pc4 = (kq & 3) * 4;
            #pragma unroll
            for (int s = 0; s < 16; ++s)
                acc[s] += f4dot(wq, *(const float4*)&rs[s * 16 + pr][pc4]);
        }
        #pragma unroll
        for (int s = 0; s < 16; ++s) hp[w - 8][s * 64 + l] = acc[s];
    }
    __syncthreads();

    {
        float v = 0.f, hsum = 0.f;
        #pragma unroll
        for (int k = 0; k < 8; ++k) { v += vp[k][t]; hsum += hp[k][t]; }
        vcomp[(size_t)bc * KIN + t] = v + 16.f * bv[t & 63];
        hcomp[(size_t)bc * KIN + t] = hsum + 16.f * bh[t & 63];
    }
}

// ---------------------------------------------------------------------------
// K2: P[ks][bc][r][n] = sum_{k in ks-chunk} A[bc][k] * B[r][n][k]
// Tile 64bc x 64n x 3r, micro 4x3x4. grid (4 n-tiles, 4 bc-tiles * KS, 2).
// ---------------------------------------------------------------------------
__global__ __launch_bounds__(256) void k2_proj(
    const float* __restrict__ vcomp, const float* __restrict__ hcomp,
    const float* __restrict__ Vw, const float* __restrict__ Hw,
    float* __restrict__ Vp, float* __restrict__ Hp, int KSplit, int KC)
{
    __shared__ float sA[32][68];
    __shared__ float sB[32][196];

    const int mat = blockIdx.z;
    const float* A = mat ? hcomp : vcomp;
    const float* B = mat ? Hw : Vw;
    float*       P = mat ? Hp : Vp;

    const int n0  = blockIdx.x * 64;
    const int bct = blockIdx.y / KSplit, ks = blockIdx.y % KSplit;
    const int bc0 = bct * 64;
    const int t   = threadIdx.x, tb = t >> 4, tn = t & 15;

    float acc[4][3][4];
    #pragma unroll
    for (int i = 0; i < 4; ++i)
        #pragma unroll
        for (int r = 0; r < 3; ++r)
            #pragma unroll
            for (int j = 0; j < 4; ++j) acc[i][r][j] = 0.f;

    const int nch = KC >> 5;
    for (int ch = 0; ch < nch; ++ch) {
        const int k0 = ks * KC + ch * 32;
        #pragma unroll
        for (int s = 0; s < 2; ++s) {               // A: 64x32
            int q = t + s * 256;
            int bcl = q >> 3, kq = q & 7;
            float4 v = *(const float4*)(A + (size_t)(bc0 + bcl) * KIN + k0 + 4 * kq);
            sA[4*kq+0][bcl] = v.x; sA[4*kq+1][bcl] = v.y;
            sA[4*kq+2][bcl] = v.z; sA[4*kq+3][bcl] = v.w;
        }
        #pragma unroll
        for (int s = 0; s < 6; ++s) {               // B: 192x32
            int q = t + s * 256;
            int rr = q >> 3, kq = q & 7;
            int r = rr >> 6, nn = rr & 63;
            float4 v = *(const float4*)(B + ((size_t)(r * 256 + n0 + nn)) * KIN + k0 + 4 * kq);
            sB[4*kq+0][rr] = v.x; sB[4*kq+1][rr] = v.y;
            sB[4*kq+2][rr] = v.z; sB[4*kq+3][rr] = v.w;
        }
        __syncthreads();

        #pragma unroll 8
        for (int kk = 0; kk < 32; ++kk) {
            float4 av = *(const float4*)&sA[kk][4 * tb];
            float4 b0 = *(const float4*)&sB[kk][0 * 64 + 4 * tn];
            float4 b1 = *(const float4*)&sB[kk][1 * 64 + 4 * tn];
            float4 b2 = *(const float4*)&sB[kk][2 * 64 + 4 * tn];
            float a_[4] = {av.x, av.y, av.z, av.w};
            float b_[3][4] = {{b0.x,b0.y,b0.z,b0.w},{b1.x,b1.y,b1.z,b1.w},{b2.x,b2.y,b2.z,b2.w}};
            #pragma unroll
            for (int i = 0; i < 4; ++i)
                #pragma unroll
                for (int r = 0; r < 3; ++r)
                    #pragma unroll
                    for (int j = 0; j < 4; ++j)
                        acc[i][r][j] += a_[i] * b_[r][j];
        }
        __syncthreads();
    }

    #pragma unroll
    for (int i = 0; i < 4; ++i)
        #pragma unroll
        for (int r = 0; r < 3; ++r) {
            float4 o = make_float4(acc[i][r][0], acc[i][r][1], acc[i][r][2], acc[i][r][3]);
            *(float4*)(P + (((size_t)ks * 256 + bc0 + 4 * tb + i) * 3 + r) * 256 + n0 + 4 * tn) = o;
        }
}

// ---------------------------------------------------------------------------
// K3: reduce split-K partials (+bias), out = V H^T (rank 3). Write-bound.
// (R6-proven scalar-store version, grid (2, 256).)
// ---------------------------------------------------------------------------
__global__ __launch_bounds__(256) void k3_outer(
    const float* __restrict__ Vp, const float* __restrict__ Hp,
    const float* __restrict__ Vb, const float* __restrict__ Hb,
    float* __restrict__ out, int KSplit)
{
    __shared__ float sh[3][256];
    __shared__ float sv[3][128];

    const int bc = blockIdx.y, nt = blockIdx.x, t = threadIdx.x;

    #pragma unroll
    for (int r = 0; r < 3; ++r) {
        float a = Hb[r * 256 + t];
        for (int ks = 0; ks < KSplit; ++ks)
            a += Hp[(((size_t)ks * 256 + bc) * 3 + r) * 256 + t];
        sh[r][t] = a;
    }
    for (int idx = t; idx < 384; idx += 256) {
        int r = idx >> 7, nn = idx & 127;
        float a = Vb[r * 256 + nt * 128 + nn];
        for (int ks = 0; ks < KSplit; ++ks)
            a += Vp[(((size_t)ks * 256 + bc) * 3 + r) * 256 + nt * 128 + nn];
        sv[r][nn] = a;
    }
    __syncthreads();

    const float h0 = sh[0][t], h1 = sh[1][t], h2 = sh[2][t];
    float* ob = out + ((size_t)bc * 256 + nt * 128) * 256;
    #pragma unroll 4
    for (int nn = 0; nn < 128; ++nn)
        ob[nn * 256 + t] = sv[0][nn] * h0 + sv[1][nn] * h1 + sv[2][nn] * h2;
}

extern "C" void kernel_launch(void* const* d_in, const int* in_sizes, int n_in,
                              void* d_out, int out_size, void* d_ws, size_t ws_size,
                              hipStream_t stream)
{
    const float* x  = (const float*)d_in[0];
    const float* pe = (const float*)d_in[1];
    const float* Wv = (const float*)d_in[2];
    const float* bv = (const float*)d_in[3];
    const float* Wh = (const float*)d_in[4];
    const float* bh = (const float*)d_in[5];
    const float* Vw = (const float*)d_in[6];
    const float* Vb = (const float*)d_in[7];
    const float* Hw = (const float*)d_in[8];
    const float* Hb = (const float*)d_in[9];
    float* out = (float*)d_out;

    // ws layout (floats)
    float* ws         = (float*)d_ws;
    float* vcomp      = ws;                    // 262144
    float* hcomp      = ws + 262144;           // 262144
    float* wqv        = ws + 524288;           // 16384
    float* wqh        = ws + 540672;           // 16384
    float* colsum_buf = ws + 557056;           // 272*4096 = 1114112
    float* rowsum_buf = ws + 1671168;          // 1114112
    float* rest       = ws + 2785280;          // split-K partials

    int KS = 1;
    if      (ws_size >= (2785280ull + 8 * 393216ull) * 4) KS = 8;
    else if (ws_size >= (2785280ull + 4 * 393216ull) * 4) KS = 4;
    else if (ws_size >= (2785280ull + 2 * 393216ull) * 4) KS = 2;
    const int KC = KIN / KS;

    float* Vp = rest;
    float* Hp = rest + (size_t)KS * 196608;

    k1_fused<<<16 + 4352, 256, 0, stream>>>(x, pe, Wv, Wh,
                                            (float4*)wqv, (float4*)wqh,
                                            colsum_buf, rowsum_buf);
    k1c<<<256, 1024, 0, stream>>>(colsum_buf, rowsum_buf,
                                  (const float4*)wqv, (const float4*)wqh,
                                  bv, bh, vcomp, hcomp);
    k2_proj<<<dim3(4, 4 * KS, 2), 256, 0, stream>>>(vcomp, hcomp, Vw, Hw,
                                                    Vp, Hp, KS, KC);
    k3_outer<<<dim3(2, 256), 256, 0, stream>>>(Vp, Hp, Vb, Hb, out, KS);
}

// Round 10
// 55.518 us; speedup vs baseline: 1.7492x; 1.2170x over previous
//
#include <hip/hip_runtime.h>

#define KIN 1024

__device__ __forceinline__ float4 f4add(float4 a, float4 b) {
    return make_float4(a.x + b.x, a.y + b.y, a.z + b.z, a.w + b.w);
}
__device__ __forceinline__ float f4dot(float4 a, float4 b) {
    return a.x * b.x + a.y * b.y + a.z * b.z + a.w * b.w;
}
__device__ __forceinline__ unsigned short f2bf(float f) {   // RNE bf16
    unsigned int u = __float_as_uint(f);
    u += 0x7FFFu + ((u >> 16) & 1u);
    return (unsigned short)(u >> 16);
}

typedef __attribute__((ext_vector_type(8))) short bf16x8;   // 8 bf16 = 4 VGPR
typedef __attribute__((ext_vector_type(4))) float f32x4;

// ---------------------------------------------------------------------------
// K1: blocks [0,16): W repack -> Wq[kq][d] float4.
//     blocks [16,4368): single-pass col/row reduction per (img, pr), img
//       0..255 = x[bc], 256..271 = pe[c]; rowsum via LDS transpose.
//     blocks [4368,5136): convert Vw/Hw (fp32, k-major) -> bf16.
// ---------------------------------------------------------------------------
__global__ __launch_bounds__(256) void k1_fused(
    const float* __restrict__ x, const float* __restrict__ pe,
    const float* __restrict__ Wv, const float* __restrict__ Wh,
    const float* __restrict__ Vw, const float* __restrict__ Hw,
    float4* __restrict__ Wqv, float4* __restrict__ Wqh,
    unsigned short* __restrict__ Vw_bf, unsigned short* __restrict__ Hw_bf,
    float* __restrict__ colsum_buf, float* __restrict__ rowsum_buf)
{
    const int blk = blockIdx.x, t = threadIdx.x;

    if (blk < 16) {                                  // --- W repack ---
        int idx = blk * 256 + t;                     // 0..4095
        int kq = idx >> 6, d = idx & 63;
        Wqv[idx] = *(const float4*)(Wv + d * 256 + 4 * kq);
        Wqh[idx] = *(const float4*)(Wh + d * 256 + 4 * kq);
        return;
    }

    if (blk >= 4368) {                               // --- Vw/Hw -> bf16 ---
        const int idx = blk - 4368;                  // 0..767
        #pragma unroll
        for (int rr = 0; rr < 2; ++rr) {
            const int row = 2 * idx + rr;            // 0..1535 (Vw then Hw)
            const float4* src = (const float4*)((row < 768)
                ? (Vw + (size_t)row * 1024)
                : (Hw + (size_t)(row - 768) * 1024));
            unsigned short* dst = ((row < 768) ? Vw_bf + (size_t)row * 1024
                                               : Hw_bf + (size_t)(row - 768) * 1024);
            float4 v = src[t];
            ushort4 o = make_ushort4(f2bf(v.x), f2bf(v.y), f2bf(v.z), f2bf(v.w));
            ((ushort4*)dst)[t] = o;
        }
        return;
    }

    __shared__ float srow[16][264];   // 16 rows x 256 cols (+8 pad)
    __shared__ float cpart[4][256];

    const int b2 = blk - 16;                         // 0..4351
    const int img = b2 >> 4, pr = b2 & 15;
    const float* ib = (img < 256) ? (x + (size_t)img * 65536)
                                  : (pe + (size_t)(img - 256) * 65536);
    const int w = t >> 6, l = t & 63;

    float4 v[4];
    const float* base = ib + (size_t)(pr + 64 * w) * 256 + 4 * l;
    #pragma unroll
    for (int j = 0; j < 4; ++j)
        v[j] = *(const float4*)(base + j * 4096);

    *(float4*)&cpart[w][4 * l] = f4add(f4add(v[0], v[1]), f4add(v[2], v[3]));

    #pragma unroll
    for (int j = 0; j < 4; ++j)
        *(float4*)&srow[4 * w + j][4 * l] = v[j];
    __syncthreads();

    {   // rowsum: thread (lr, pc) sums 16 strided elements of one row
        const int lr = t >> 4, pc = t & 15;
        float s = 0.f;
        #pragma unroll
        for (int i = 0; i < 16; ++i) s += srow[lr][pc + 16 * i];
        const int grow = pr + 16 * lr;
        rowsum_buf[(size_t)img * 4096 + grow * 16 + pc] = s;
    }
    {   // colsum combine
        colsum_buf[(size_t)img * 4096 + pr * 256 + t] =
            cpart[0][t] + cpart[1][t] + cpart[2][t] + cpart[3][t];
    }
}

// ---------------------------------------------------------------------------
// K1c: per bc, project (colsum incl. pe) with Wqv and (rowsum incl. pe) with
// Wqh -> bf16 vcomp/hcomp (pe + 16x bias folded). Same as R9 except the
// outputs are bf16 (for the MFMA K2).
// ---------------------------------------------------------------------------
__global__ __launch_bounds__(1024) void k1c(
    const float* __restrict__ colsum_buf, const float* __restrict__ rowsum_buf,
    const float4* __restrict__ Wqv, const float4* __restrict__ Wqh,
    const float* __restrict__ bv, const float* __restrict__ bh,
    unsigned short* __restrict__ vcomp_bf, unsigned short* __restrict__ hcomp_bf)
{
    __shared__ float cs[16][256];
    __shared__ float rs[256][16];
    __shared__ float vp[8][1024];
    __shared__ float hp[8][1024];

    const int bc = blockIdx.x, c = bc & 15, t = threadIdx.x;

    {
        float4 a = ((const float4*)(colsum_buf + (size_t)bc * 4096))[t];
        float4 p = ((const float4*)(colsum_buf + (size_t)(256 + c) * 4096))[t];
        ((float4*)cs)[t] = f4add(a, p);
        float4 b = ((const float4*)(rowsum_buf + (size_t)bc * 4096))[t];
        float4 q = ((const float4*)(rowsum_buf + (size_t)(256 + c) * 4096))[t];
        ((float4*)rs)[t] = f4add(b, q);
    }
    __syncthreads();

    const int w = t >> 6, l = t & 63;
    if (w < 8) {
        const int kq0 = w * 8;
        float acc[16];
        #pragma unroll
        for (int s = 0; s < 16; ++s) acc[s] = 0.f;
        #pragma unroll 2
        for (int kq = kq0; kq < kq0 + 8; ++kq) {
            float4 wq = Wqv[kq * 64 + l];
            const int pr = kq >> 2, pc4 = (kq & 3) * 4;
            #pragma unroll
            for (int s = 0; s < 16; ++s)
                acc[s] += f4dot(wq, *(const float4*)&cs[pr][s * 16 + pc4]);
        }
        #pragma unroll
        for (int s = 0; s < 16; ++s) vp[w][s * 64 + l] = acc[s];
    } else {
        const int kq0 = (w - 8) * 8;
        float acc[16];
        #pragma unroll
        for (int s = 0; s < 16; ++s) acc[s] = 0.f;
        #pragma unroll 2
        for (int kq = kq0; kq < kq0 + 8; ++kq) {
            float4 wq = Wqh[kq * 64 + l];
            const int pr = kq >> 2, pc4 = (kq & 3) * 4;
            #pragma unroll
            for (int s = 0; s < 16; ++s)
                acc[s] += f4dot(wq, *(const float4*)&rs[s * 16 + pr][pc4]);
        }
        #pragma unroll
        for (int s = 0; s < 16; ++s) hp[w - 8][s * 64 + l] = acc[s];
    }
    __syncthreads();

    {
        float v = 0.f, hsum = 0.f;
        #pragma unroll
        for (int k = 0; k < 8; ++k) { v += vp[k][t]; hsum += hp[k][t]; }
        vcomp_bf[(size_t)bc * KIN + t] = f2bf(v + 16.f * bv[t & 63]);
        hcomp_bf[(size_t)bc * KIN + t] = f2bf(hsum + 16.f * bh[t & 63]);
    }
}

// ---------------------------------------------------------------------------
// K2 (MFMA bf16): P[ks][bc][r][n] = sum_k A[bc][k]*B[rn][k], A=vcomp_bf,
// B=W_bf, both k-major. Block tile 64bc x 64rn; 4 waves, wave w owns bc rows
// w*16..w*16+15 (4 n-frags of 16). mfma_f32_16x16x32_bf16; C/D layout:
// n = lane&15, m = (lane>>4)*4 + reg (HW-verified). K staged in 128-chunks.
// grid (12 rn-tiles, 4 bct * KS, 2 mats).
// ---------------------------------------------------------------------------
__global__ __launch_bounds__(256) void k2_mfma(
    const unsigned short* __restrict__ vcomp_bf,
    const unsigned short* __restrict__ hcomp_bf,
    const unsigned short* __restrict__ Vw_bf,
    const unsigned short* __restrict__ Hw_bf,
    float* __restrict__ Vp, float* __restrict__ Hp, int KSplit, int KC)
{
    __shared__ unsigned short As[64][136];   // 64 bc x 128 k (+8 pad)
    __shared__ unsigned short Bs[64][136];   // 64 rn x 128 k (+8 pad)

    const int mat = blockIdx.z;
    const unsigned short* A = mat ? hcomp_bf : vcomp_bf;
    const unsigned short* B = mat ? Hw_bf : Vw_bf;
    float*                P = mat ? Hp : Vp;

    const int rn0 = blockIdx.x * 64;                  // 0..704
    const int bct = blockIdx.y / KSplit, ks = blockIdx.y % KSplit;
    const int bc0 = bct * 64;
    const int t = threadIdx.x, w = t >> 6, l = t & 63;

    f32x4 acc[4];
    #pragma unroll
    for (int nf = 0; nf < 4; ++nf) acc[nf] = (f32x4)(0.f);

    const int nch = KC >> 7;                          // chunks of 128 k
    for (int ch = 0; ch < nch; ++ch) {
        const int k0 = ks * KC + ch * 128;
        #pragma unroll
        for (int j = 0; j < 4; ++j) {                 // stage A and B chunks
            const int idx = t + j * 256;              // 0..1023
            const int row = idx >> 4, c16 = idx & 15;
            uint4 va = *(const uint4*)(A + (size_t)(bc0 + row) * KIN + k0 + c16 * 8);
            *(uint4*)&As[row][c16 * 8] = va;
            uint4 vb = *(const uint4*)(B + (size_t)(rn0 + row) * KIN + k0 + c16 * 8);
            *(uint4*)&Bs[row][c16 * 8] = vb;
        }
        __syncthreads();

        #pragma unroll
        for (int kst = 0; kst < 4; ++kst) {           // 4 x K=32 steps
            const int kl = kst * 32 + (l >> 4) * 8;
            bf16x8 a = *(const bf16x8*)&As[w * 16 + (l & 15)][kl];
            #pragma unroll
            for (int nf = 0; nf < 4; ++nf) {
                bf16x8 b = *(const bf16x8*)&Bs[nf * 16 + (l & 15)][kl];
                acc[nf] = __builtin_amdgcn_mfma_f32_16x16x32_bf16(a, b, acc[nf], 0, 0, 0);
            }
        }
        __syncthreads();
    }

    // epilogue: store fp32 partials (layout identical to old k2's P)
    const int r = rn0 >> 8;
    const int nbase = rn0 & 255;
    #pragma unroll
    for (int nf = 0; nf < 4; ++nf) {
        const int n = nbase + nf * 16 + (l & 15);
        #pragma unroll
        for (int q = 0; q < 4; ++q) {
            const int m = (l >> 4) * 4 + q;
            const int bc = bc0 + w * 16 + m;
            P[(((size_t)ks * 256 + bc) * 3 + r) * 256 + n] = acc[nf][q];
        }
    }
}

// ---------------------------------------------------------------------------
// K3: reduce split-K partials (+bias), out = V H^T (rank 3). Write-bound.
// (R6/R9-proven scalar-store version, grid (2, 256).)
// ---------------------------------------------------------------------------
__global__ __launch_bounds__(256) void k3_outer(
    const float* __restrict__ Vp, const float* __restrict__ Hp,
    const float* __restrict__ Vb, const float* __restrict__ Hb,
    float* __restrict__ out, int KSplit)
{
    __shared__ float sh[3][256];
    __shared__ float sv[3][128];

    const int bc = blockIdx.y, nt = blockIdx.x, t = threadIdx.x;

    #pragma unroll
    for (int r = 0; r < 3; ++r) {
        float a = Hb[r * 256 + t];
        for (int ks = 0; ks < KSplit; ++ks)
            a += Hp[(((size_t)ks * 256 + bc) * 3 + r) * 256 + t];
        sh[r][t] = a;
    }
    for (int idx = t; idx < 384; idx += 256) {
        int r = idx >> 7, nn = idx & 127;
        float a = Vb[r * 256 + nt * 128 + nn];
        for (int ks = 0; ks < KSplit; ++ks)
            a += Vp[(((size_t)ks * 256 + bc) * 3 + r) * 256 + nt * 128 + nn];
        sv[r][nn] = a;
    }
    __syncthreads();

    const float h0 = sh[0][t], h1 = sh[1][t], h2 = sh[2][t];
    float* ob = out + ((size_t)bc * 256 + nt * 128) * 256;
    #pragma unroll 4
    for (int nn = 0; nn < 128; ++nn)
        ob[nn * 256 + t] = sv[0][nn] * h0 + sv[1][nn] * h1 + sv[2][nn] * h2;
}

extern "C" void kernel_launch(void* const* d_in, const int* in_sizes, int n_in,
                              void* d_out, int out_size, void* d_ws, size_t ws_size,
                              hipStream_t stream)
{
    const float* x  = (const float*)d_in[0];
    const float* pe = (const float*)d_in[1];
    const float* Wv = (const float*)d_in[2];
    const float* bv = (const float*)d_in[3];
    const float* Wh = (const float*)d_in[4];
    const float* bh = (const float*)d_in[5];
    const float* Vw = (const float*)d_in[6];
    const float* Vb = (const float*)d_in[7];
    const float* Hw = (const float*)d_in[8];
    const float* Hb = (const float*)d_in[9];
    float* out = (float*)d_out;

    // ws layout (float-slot offsets)
    float* ws          = (float*)d_ws;
    float* wqv         = ws;                         // 16384
    float* wqh         = ws + 16384;                 // 16384
    float* colsum_buf  = ws + 32768;                 // 272*4096 = 1114112
    float* rowsum_buf  = ws + 1146880;               // 1114112
    unsigned short* vcomp_bf = (unsigned short*)(ws + 2260992);  // 131072 fl
    unsigned short* hcomp_bf = (unsigned short*)(ws + 2392064);  // 131072 fl
    unsigned short* Vw_bf    = (unsigned short*)(ws + 2523136);  // 393216 fl
    unsigned short* Hw_bf    = (unsigned short*)(ws + 2916352);  // 393216 fl
    float* rest        = ws + 3309568;               // split-K partials

    int KS = 1;
    if      (ws_size >= (3309568ull + 8 * 393216ull) * 4) KS = 8;
    else if (ws_size >= (3309568ull + 4 * 393216ull) * 4) KS = 4;
    else if (ws_size >= (3309568ull + 2 * 393216ull) * 4) KS = 2;
    const int KC = KIN / KS;

    float* Vp = rest;
    float* Hp = rest + (size_t)KS * 196608;

    k1_fused<<<16 + 4352 + 768, 256, 0, stream>>>(
        x, pe, Wv, Wh, Vw, Hw, (float4*)wqv, (float4*)wqh,
        Vw_bf, Hw_bf, colsum_buf, rowsum_buf);
    k1c<<<256, 1024, 0, stream>>>(colsum_buf, rowsum_buf,
                                  (const float4*)wqv, (const float4*)wqh,
                                  bv, bh, vcomp_bf, hcomp_bf);
    k2_mfma<<<dim3(12, 4 * KS, 2), 256, 0, stream>>>(
        vcomp_bf, hcomp_bf, Vw_bf, Hw_bf, Vp, Hp, KS, KC);
    k3_outer<<<dim3(2, 256), 256, 0, stream>>>(Vp, Hp, Vb, Hb, out, KS);
}